// Round 4
// baseline (1152.120 us; speedup 1.0000x reference)
//
#include <hip/hip_runtime.h>
#include <math.h>

// Problem constants (B,S,H fixed by reference setup_inputs)
#define BB 32
#define SS 4096
#define HH 1024
#define NCHUNK 64               // grid 64*32 = 2048 blocks
#define CHUNK (SS / NCHUNK)     // 64 s-rows per block; 16 contiguous rows per wave
#define NEG_INF9 (-1.0e9f)

// ---------------------------------------------------------------------------
// Two interleaved wave64 all-reduce(sum) DPP trees (independent chains hide
// each other's ~8cy DPP latency). Results broadcast via readlane -> SGPR.
// ---------------------------------------------------------------------------
__device__ __forceinline__ void dpp_allreduce_add2(float& a, float& b) {
#define DPP_STEP(ctl)                                                                   \
    {                                                                                   \
        const int ta = __builtin_amdgcn_update_dpp(0, __float_as_int(a), ctl, 0xf, 0xf, false); \
        const int tb = __builtin_amdgcn_update_dpp(0, __float_as_int(b), ctl, 0xf, 0xf, false); \
        a += __int_as_float(ta);                                                        \
        b += __int_as_float(tb);                                                        \
    }
    DPP_STEP(0x111)  // row_shr:1
    DPP_STEP(0x112)  // row_shr:2
    DPP_STEP(0x114)  // row_shr:4
    DPP_STEP(0x118)  // row_shr:8
    DPP_STEP(0x142)  // row_bcast:15
    DPP_STEP(0x143)  // row_bcast:31
#undef DPP_STEP
    a = __int_as_float(__builtin_amdgcn_readlane(__float_as_int(a), 63));
    b = __int_as_float(__builtin_amdgcn_readlane(__float_as_int(b), 63));
}

__device__ __forceinline__ float dpp_allreduce_add(float x) {
    int t;
    t = __builtin_amdgcn_update_dpp(0, __float_as_int(x), 0x111, 0xf, 0xf, false);
    x += __int_as_float(t);
    t = __builtin_amdgcn_update_dpp(0, __float_as_int(x), 0x112, 0xf, 0xf, false);
    x += __int_as_float(t);
    t = __builtin_amdgcn_update_dpp(0, __float_as_int(x), 0x114, 0xf, 0xf, false);
    x += __int_as_float(t);
    t = __builtin_amdgcn_update_dpp(0, __float_as_int(x), 0x118, 0xf, 0xf, false);
    x += __int_as_float(t);
    t = __builtin_amdgcn_update_dpp(0, __float_as_int(x), 0x142, 0xf, 0xf, false);
    x += __int_as_float(t);
    t = __builtin_amdgcn_update_dpp(0, __float_as_int(x), 0x143, 0xf, 0xf, false);
    x += __int_as_float(t);
    return __int_as_float(__builtin_amdgcn_readlane(__float_as_int(x), 63));
}

// ---------------- Kernel 1: q = query @ W^T  (+ zero per-batch done counters) ----------------
__global__ __launch_bounds__(256) void qproj_kernel(const float* __restrict__ query,
                                                    const float* __restrict__ W,
                                                    float* __restrict__ q,
                                                    int* __restrict__ done_cnt) {
    if (blockIdx.x == 0 && blockIdx.y == 0 && threadIdx.x < BB) done_cnt[threadIdx.x] = 0;

    const int b    = blockIdx.y;
    const int wave = threadIdx.x >> 6;
    const int lane = threadIdx.x & 63;

    const float4* qp = (const float4*)(query + (size_t)b * HH);
    float4 qv[4];
#pragma unroll
    for (int r = 0; r < 4; ++r) qv[r] = qp[r * 64 + lane];

    const int obase = blockIdx.x * 64 + wave * 16;
    for (int i = 0; i < 16; ++i) {
        const int o = obase + i;
        const float4* wp = (const float4*)(W + (size_t)o * HH);
        float acc = 0.f;
#pragma unroll
        for (int r = 0; r < 4; ++r) {
            const float4 wv = wp[r * 64 + lane];
            acc += wv.x * qv[r].x + wv.y * qv[r].y + wv.z * qv[r].z + wv.w * qv[r].w;
        }
        const float s = dpp_allreduce_add(acc);
        if (lane == 0) q[(size_t)b * HH + o] = s;
    }
}

// ---------------- Kernel 2: fused scores+softmax+partials + last-block combine ----------------
// Register-path streaming (the measured-best structure). Each wave owns 16 CONTIGUOUS
// key rows, processed as 8 row-pair iterations with a one-pair-ahead register prefetch
// (8 KB/wave in flight across the reduce/softmax chain). Softmax state is wave-uniform
// scalar (DPP reduce + readlane); acc rescale only when the running max moves (exact).
__global__ __launch_bounds__(256, 4) void attn_fused_kernel(const float* __restrict__ q,
                                                            const float* __restrict__ keys,
                                                            const int* __restrict__ mask,
                                                            float* __restrict__ weights,
                                                            float* __restrict__ pm,
                                                            float* __restrict__ pl,
                                                            float* __restrict__ pO,
                                                            int* __restrict__ done_cnt,
                                                            float* __restrict__ context) {
    const int b    = blockIdx.y;
    const int c    = blockIdx.x;
    const int tid  = threadIdx.x;
    const int wave = tid >> 6;
    const int lane = tid & 63;

    const float4* qp = (const float4*)(q + (size_t)b * HH);
    float4 qv[4];
#pragma unroll
    for (int r = 0; r < 4; ++r) qv[r] = qp[r * 64 + lane];

    const size_t bbase = (size_t)b * SS;
    const int row0 = c * CHUNK + wave * 16;               // wave's 16 contiguous rows
    const float4* kbase = (const float4*)(keys + (bbase + row0) * HH) + lane;

    float4 ka[2][4], kb[2][4];
    int2   mk[2];

    // prologue: load pair 0 (rows row0, row0+1)
#pragma unroll
    for (int r = 0; r < 4; ++r) { ka[0][r] = kbase[r * 64]; kb[0][r] = kbase[256 + r * 64]; }
    mk[0] = *(const int2*)(mask + bbase + row0);

    float m = -INFINITY;
    float l = 0.f;
    float4 acc[4];
#pragma unroll
    for (int r = 0; r < 4; ++r) acc[r] = make_float4(0.f, 0.f, 0.f, 0.f);

#pragma unroll
    for (int i = 0; i < 8; ++i) {
        const int cur = i & 1, nxt = cur ^ 1;
        // ---- prefetch pair i+1 (rows row0+2i+2, +3): in flight across the chain below
        if (i < 7) {
            const float4* p0 = kbase + (size_t)(i + 1) * 512;
#pragma unroll
            for (int r = 0; r < 4; ++r) { ka[nxt][r] = p0[r * 64]; kb[nxt][r] = p0[256 + r * 64]; }
            mk[nxt] = *(const int2*)(mask + bbase + row0 + 2 * (i + 1));
        }

        // ---- dot products for current pair
        float x0 = 0.f, x1 = 0.f;
#pragma unroll
        for (int r = 0; r < 4; ++r) {
            x0 += ka[cur][r].x * qv[r].x + ka[cur][r].y * qv[r].y + ka[cur][r].z * qv[r].z + ka[cur][r].w * qv[r].w;
            x1 += kb[cur][r].x * qv[r].x + kb[cur][r].y * qv[r].y + kb[cur][r].z * qv[r].z + kb[cur][r].w * qv[r].w;
        }
        dpp_allreduce_add2(x0, x1);      // -> wave-uniform scalars
        float sc0 = x0, sc1 = x1;

        const int mx = __builtin_amdgcn_readfirstlane(mk[cur].x);
        const int my = __builtin_amdgcn_readfirstlane(mk[cur].y);
        if (mx != 0) sc0 = NEG_INF9;
        if (my != 0) sc1 = NEG_INF9;
        if (lane == 0) *(float2*)(weights + bbase + row0 + 2 * i) = make_float2(sc0, sc1);

        const float mnew = fmaxf(m, fmaxf(sc0, sc1));
        if (mnew > m) {  // wave-uniform branch; exact (skip <=> scale==1). m=-inf first iter -> scale 0
            const float scale = __expf(m - mnew);
            l *= scale;
#pragma unroll
            for (int r = 0; r < 4; ++r) {
                acc[r].x *= scale; acc[r].y *= scale; acc[r].z *= scale; acc[r].w *= scale;
            }
            m = mnew;
        }
        const float p0 = __expf(sc0 - m);
        const float p1 = __expf(sc1 - m);
        l += p0 + p1;
#pragma unroll
        for (int r = 0; r < 4; ++r) {
            acc[r].x += p0 * ka[cur][r].x + p1 * kb[cur][r].x;
            acc[r].y += p0 * ka[cur][r].y + p1 * kb[cur][r].y;
            acc[r].z += p0 * ka[cur][r].z + p1 * kb[cur][r].z;
            acc[r].w += p0 * ka[cur][r].w + p1 * kb[cur][r].w;
        }
    }

    // ---- combine the 4 waves of this block via LDS
    __shared__ float4 sO[4][256];  // 16 KB
    __shared__ float  sm[4], sl[4];
    __shared__ int    s_last;
#pragma unroll
    for (int r = 0; r < 4; ++r) sO[wave][r * 64 + lane] = acc[r];
    if (lane == 0) { sm[wave] = m; sl[wave] = l; }
    __syncthreads();

    const float M = fmaxf(fmaxf(sm[0], sm[1]), fmaxf(sm[2], sm[3]));
    float f[4];
#pragma unroll
    for (int w = 0; w < 4; ++w) f[w] = __expf(sm[w] - M);
    const float L = sl[0] * f[0] + sl[1] * f[1] + sl[2] * f[2] + sl[3] * f[3];

    float4 o = make_float4(0.f, 0.f, 0.f, 0.f);
#pragma unroll
    for (int w = 0; w < 4; ++w) {
        const float4 v = sO[w][tid];
        o.x += f[w] * v.x; o.y += f[w] * v.y; o.z += f[w] * v.z; o.w += f[w] * v.w;
    }
    ((float4*)(pO + ((size_t)b * NCHUNK + c) * HH))[tid] = o;
    if (tid == 0) { pm[b * NCHUNK + c] = M; pl[b * NCHUNK + c] = L; }

    // ---- last-block-per-batch combine (split-K: release fence, count, acquire fence)
    __threadfence();
    __syncthreads();
    if (tid == 0) s_last = (atomicAdd(&done_cnt[b], 1) == NCHUNK - 1);
    __syncthreads();
    if (!s_last) return;
    __threadfence();

    float Mb = -INFINITY;
#pragma unroll 8
    for (int cc = 0; cc < NCHUNK; ++cc) Mb = fmaxf(Mb, pm[b * NCHUNK + cc]);
    float Lb = 0.f;
#pragma unroll 8
    for (int cc = 0; cc < NCHUNK; ++cc) Lb += pl[b * NCHUNK + cc] * __expf(pm[b * NCHUNK + cc] - Mb);
    const float invL = 1.f / Lb;

    const float4* pO4 = (const float4*)pO;
    float4 o2 = make_float4(0.f, 0.f, 0.f, 0.f);
#pragma unroll 8
    for (int cc = 0; cc < NCHUNK; ++cc) {
        const float g = __expf(pm[b * NCHUNK + cc] - Mb) * invL;
        const float4 v = pO4[((size_t)b * NCHUNK + cc) * (HH / 4) + tid];
        o2.x += g * v.x; o2.y += g * v.y; o2.z += g * v.z; o2.w += g * v.w;
    }
    ((float4*)(context + (size_t)b * HH))[tid] = o2;

#pragma unroll
    for (int k = 0; k < SS / 256; ++k) {
        const size_t idx = bbase + k * 256 + tid;
        const float sc = weights[idx];
        weights[idx] = __expf(sc - Mb) * invL;  // masked -1e9 -> exactly 0
    }
}

extern "C" void kernel_launch(void* const* d_in, const int* in_sizes, int n_in,
                              void* d_out, int out_size, void* d_ws, size_t ws_size,
                              hipStream_t stream) {
    const float* query = (const float*)d_in[0];  // [B,1,H]
    const float* keys  = (const float*)d_in[1];  // [B,S,H]
    const int*   mask  = (const int*)d_in[2];    // [B,S] bool->int
    const float* W     = (const float*)d_in[3];  // [H,H]

    float* context = (float*)d_out;                     // B*H floats
    float* weights = (float*)d_out + (size_t)BB * HH;   // B*S floats

    float* q    = (float*)d_ws;                         // B*H
    float* pm   = q + (size_t)BB * HH;                  // B*NCHUNK
    float* pl   = pm + BB * NCHUNK;                     // B*NCHUNK
    float* pO   = pl + BB * NCHUNK;                     // B*NCHUNK*H (8 MB)
    int*   done = (int*)(pO + (size_t)BB * NCHUNK * HH);// B counters

    qproj_kernel<<<dim3(HH / 64, BB), 256, 0, stream>>>(query, W, q, done);
    attn_fused_kernel<<<dim3(NCHUNK, BB), 256, 0, stream>>>(q, keys, mask, weights, pm, pl, pO,
                                                            done, context);
}